// Round 1
// baseline (463.922 us; speedup 1.0000x reference)
//
#include <hip/hip_runtime.h>
#include <math.h>

typedef __attribute__((ext_vector_type(8))) short short8;
typedef __attribute__((ext_vector_type(4))) float f32x4;

static __device__ __forceinline__ unsigned short f2bf(float f) {
  union { float f; unsigned int u; } x; x.f = f;
  unsigned int r = x.u + 0x7fffu + ((x.u >> 16) & 1u);  // RNE
  return (unsigned short)(r >> 16);
}
static __device__ __forceinline__ float bf2f(unsigned int u) {
  union { unsigned int u; float f; } x; x.u = u << 16; return x.f;
}

// ---------------------------------------------------------------------------
// Block 0: int64-vs-int32 edge_index detection. ALL blocks: zero deg32 slab
// (padN*32 ints: one 128B line of 32 shard-counters per node).
__global__ void k_flag(const unsigned int* __restrict__ w, int nSample,
                       unsigned int* __restrict__ flag,
                       int* __restrict__ deg32, int nInts) {
  int4* d4 = (int4*)deg32;
  int n4 = nInts >> 2;
  for (int i = blockIdx.x * 256 + threadIdx.x; i < n4; i += gridDim.x * 256)
    d4[i] = make_int4(0, 0, 0, 0);
  if (blockIdx.x != 0) return;
  __shared__ unsigned int red[256];
  unsigned int v = 0;
  for (int i = threadIdx.x; i < nSample; i += 256) v |= w[2 * i + 1];
  red[threadIdx.x] = v;
  __syncthreads();
  for (int s = 128; s > 0; s >>= 1) {
    if (threadIdx.x < s) red[threadIdx.x] |= red[threadIdx.x + s];
    __syncthreads();
  }
  if (threadIdx.x == 0) flag[0] = red[0];  // nonzero => int32 layout
}

// ---------------------------------------------------------------------------
// MFMA node GEMM body. INLINEW: build B fragments directly from f32 W0/W1
// (no dependency on prep blocks -> safe to co-dispatch in one mega kernel).
// MFMA layouts (gfx950, verified): A[m=lane&15][k=(lane>>4)*8+j],
// B[k][n=lane&15], C/D col=lane&15, row=(lane>>4)*4+reg.
template <int K, bool BF16IN, int NTILES, bool INLINEW>
__device__ __forceinline__ void ngemm_body(
    const void* __restrict__ Xv, const unsigned short* __restrict__ WnT,
    const float* __restrict__ W0f, const float* __restrict__ W1f,
    unsigned short* __restrict__ Y0, unsigned short* __restrict__ Y1,
    int N, int blk, unsigned short* __restrict__ sX) {
  constexpr int STR = K + 8;
  constexpr int NC = K / 32;
  const int tid = threadIdx.x;
  const int wv = tid >> 6, lane = tid & 63;
  const int m = lane & 15, q = lane >> 4;
  const int row0 = blk * 64;

  short8 bB[NTILES][NC];
#pragma unroll
  for (int ct = 0; ct < NTILES; ++ct)
#pragma unroll
    for (int c = 0; c < NC; ++c) {
      if constexpr (INLINEW) {
        int n = (NTILES == 2) ? (wv * 32 + ct * 16 + m) : (wv * 16 + m);
        const float* Wf = (n < 64) ? W0f : W1f;
        int nn = n & 63;
        union { short8 s; unsigned short h[8]; } ub;
#pragma unroll
        for (int j = 0; j < 8; ++j)
          ub.h[j] = f2bf(Wf[(size_t)(c * 32 + q * 8 + j) * 64 + nn]);
        bB[ct][c] = ub.s;
      } else {
        int n = (NTILES == 2) ? (wv * 32 + ct * 16 + m) : (wv * 16 + m);
        bB[ct][c] = *(const short8*)(WnT + (size_t)n * K + c * 32 + q * 8);
      }
    }

#pragma unroll
  for (int i = 0; i < K / 16; ++i) {
    int f = tid + 256 * i;
    int r = f / (K / 4);
    int c4 = f % (K / 4);
    int rr = row0 + r; if (rr >= N) rr = N - 1;
    uint2 pk;
    if constexpr (BF16IN) {
      pk = *(const uint2*)((const unsigned short*)Xv + (size_t)rr * K + c4 * 4);
    } else {
      float4 v = *(const float4*)((const float*)Xv + (size_t)rr * K + c4 * 4);
      pk.x = (unsigned int)f2bf(v.x) | ((unsigned int)f2bf(v.y) << 16);
      pk.y = (unsigned int)f2bf(v.z) | ((unsigned int)f2bf(v.w) << 16);
    }
    *(uint2*)(sX + r * STR + c4 * 4) = pk;
  }
  __syncthreads();

  f32x4 acc[4][NTILES];
#pragma unroll
  for (int rt = 0; rt < 4; ++rt)
#pragma unroll
    for (int ct = 0; ct < NTILES; ++ct)
#pragma unroll
      for (int r = 0; r < 4; ++r) acc[rt][ct][r] = 0.f;

#pragma unroll
  for (int c = 0; c < NC; ++c) {
    short8 a[4];
#pragma unroll
    for (int rt = 0; rt < 4; ++rt)
      a[rt] = *(const short8*)(sX + (rt * 16 + m) * STR + c * 32 + q * 8);
#pragma unroll
    for (int rt = 0; rt < 4; ++rt)
#pragma unroll
      for (int ct = 0; ct < NTILES; ++ct)
        acc[rt][ct] = __builtin_amdgcn_mfma_f32_16x16x32_bf16(a[rt], bB[ct][c], acc[rt][ct], 0, 0, 0);
  }

#pragma unroll
  for (int rt = 0; rt < 4; ++rt)
#pragma unroll
    for (int ct = 0; ct < NTILES; ++ct) {
      unsigned short* Yw;
      int n;
      if constexpr (NTILES == 2) {
        Yw = (wv < 2) ? Y0 : Y1;
        n = (wv & 1) * 32 + ct * 16 + m;
      } else {
        Yw = Y0;
        n = wv * 16 + m;
      }
#pragma unroll
      for (int reg = 0; reg < 4; ++reg) {
        int row = row0 + rt * 16 + q * 4 + reg;
        if (row < N) Yw[(size_t)row * 64 + n] = f2bf(acc[rt][ct][reg]);
      }
    }
}

template <int K, bool BF16IN, int NTILES>
__global__ __launch_bounds__(256) void k_ngemm(
    const void* __restrict__ Xv, const unsigned short* __restrict__ WnT,
    unsigned short* __restrict__ Y0, unsigned short* __restrict__ Y1, int N) {
  __shared__ __align__(16) unsigned short sX[64 * (K + 8)];
  ngemm_body<K, BF16IN, NTILES, false>(Xv, WnT, nullptr, nullptr, Y0, Y1, N,
                                       blockIdx.x, sX);
}

// ---------------------------------------------------------------------------
// MEGA1: pack decode's atomic-fabric shadow with ALL independent work.
// Decode atomics are 32-way node-line-sharded: deg32[t*32 + (di&31)] puts 32
// shard counters of one node on ONE 128B line -> per-line atomic convoy drops
// from ~320 ops to ~max-degree (~28); per-address from ~10 to ~1.25.
__global__ __launch_bounds__(256) void k_mega1(
    const unsigned int* __restrict__ w, const unsigned int* __restrict__ flag,
    int E, int nDec, int nWork, int gB, int nConvThreads,
    int* __restrict__ src, int* __restrict__ tgt,
    int* __restrict__ posin, int* __restrict__ deg32,
    const float* __restrict__ x, unsigned short* __restrict__ Yl,
    unsigned short* __restrict__ Yr, int N,
    const float* __restrict__ We2, const float* __restrict__ Wo1,
    const float* __restrict__ be2, const float* __restrict__ bo1,
    const float* __restrict__ We1,
    const float* __restrict__ Wl0, const float* __restrict__ Wr0,
    const float* __restrict__ Wl1, const float* __restrict__ Wr1,
    unsigned short* __restrict__ W25T, unsigned short* __restrict__ We1T,
    unsigned short* __restrict__ Wo1T, float* __restrict__ cvec,
    unsigned short* __restrict__ WnT1,
    const float4* __restrict__ ef, uint2* __restrict__ eb) {
  __shared__ __align__(16) char smem[64 * 136 * 2];   // 17408 B, union use
  const int tid = threadIdx.x;
  const int tot = nDec + nWork;
  // proportional striping: decode-count before this block
  const int di  = (int)(((long long)blockIdx.x * nDec) / tot);
  const int di1 = (int)(((long long)(blockIdx.x + 1) * nDec) / tot);

  if (di1 > di) {
    // ---- decode block #di
    int e = di * 256 + tid;
    if (e >= E) return;
    int s, t;
    if (flag[0]) { s = (int)w[e]; t = (int)w[E + e]; }
    else         { s = (int)w[2 * e]; t = (int)w[2 * (E + e)]; }
    src[e] = s;
    tgt[e] = t;
    posin[e] = atomicAdd(deg32 + (size_t)t * 32 + (di & 31), 1);
    return;
  }
  const int wi = blockIdx.x - di;
  if (wi == 0) {
    // ---- prep: W25T=(We2@Wo1)^T, Wo1T, We1T, cvec (Wo1 staged in smem)
    float* sB = (float*)smem;
    for (int i = tid; i < 1024; i += 256)
      *(float4*)&sB[i * 4] = *(const float4*)(Wo1 + i * 4);
    __syncthreads();
    for (int idx = tid; idx < 4096; idx += 256) {
      int k = idx >> 6, n = idx & 63;   // k wave-uniform -> We2 scalarizes
      float s = 0.f;
#pragma unroll 8
      for (int mm = 0; mm < 64; ++mm) s = fmaf(We2[k * 64 + mm], sB[mm * 64 + n], s);
      W25T[n * 64 + k] = f2bf(s);
      Wo1T[n * 64 + k] = f2bf(sB[k * 64 + n]);
    }
    for (int idx = tid; idx < 2048; idx += 256) {
      int n = idx >> 5, k = idx & 31;
      We1T[n * 32 + k] = (k < 16) ? f2bf(We1[k * 64 + n]) : (unsigned short)0;
    }
    if (tid < 64) {
      float s = bo1[tid];
#pragma unroll 8
      for (int mm = 0; mm < 64; ++mm) s = fmaf(be2[mm], sB[mm * 64 + tid], s);
      cvec[tid] = s;
    }
  } else if (wi <= 32) {
    // ---- WnT1 transpose (128x64)
    int idx = (wi - 1) * 256 + tid;
    int n = idx >> 6, k = idx & 63;
    float v = (n < 64) ? Wl1[(size_t)k * 64 + n] : Wr1[(size_t)k * 64 + (n - 64)];
    WnT1[idx] = f2bf(v);
  } else if (wi < 33 + gB) {
    // ---- layer-0 GEMM (inline f32 weights)
    ngemm_body<128, false, 2, true>(x, nullptr, Wl0, Wr0, Yl, Yr, N,
                                    wi - 33, (unsigned short*)smem);
  } else {
    // ---- eattr f32 -> bf16
    int gid = (wi - 33 - gB) * 256 + tid;
    int nItems = E * 4;
    for (int i = gid; i < nItems; i += nConvThreads) {
      float4 v = ef[i];
      uint2 pk;
      pk.x = (unsigned int)f2bf(v.x) | ((unsigned int)f2bf(v.y) << 16);
      pk.y = (unsigned int)f2bf(v.z) | ((unsigned int)f2bf(v.w) << 16);
      eb[i] = pk;
    }
  }
}

// ---------------------------------------------------------------------------
// Hierarchical exclusive scan over per-node totals (sum of 32 shard counters).
// Block b covers nodes [b*2048, b*2048+2048) = 65536 ints of the deg32 slab.
__global__ __launch_bounds__(256) void k_scan1(const int* __restrict__ deg32,
                                               int* __restrict__ bsum) {
  __shared__ int wsum[4];
  const int tid = threadIdx.x, lane = tid & 63, wid = tid >> 6;
  const int* p = deg32 + (size_t)blockIdx.x * 65536 + (size_t)tid * 4;
  int s = 0;
#pragma unroll 8
  for (int i = 0; i < 64; ++i) {
    int4 v = *(const int4*)(p + (size_t)i * 1024);
    s += v.x + v.y + v.z + v.w;
  }
#pragma unroll
  for (int off = 1; off < 64; off <<= 1) s += __shfl_xor(s, off, 64);
  if (lane == 0) wsum[wid] = s;
  __syncthreads();
  if (tid == 0) bsum[blockIdx.x] = wsum[0] + wsum[1] + wsum[2] + wsum[3];
}

__global__ void k_scan2(const int* __restrict__ bsum, int* __restrict__ boff,
                        int nB) {
  int lane = threadIdx.x;
  int v = (lane < nB) ? bsum[lane] : 0;
  int incl = v;
#pragma unroll
  for (int off = 1; off < 64; off <<= 1) {
    int t = __shfl_up(incl, off, 64);
    if (lane >= off) incl += t;
  }
  if (lane < nB) boff[lane] = incl - v;
}

// scan3: per-node rowptr (exclusive scan of node totals) PLUS per-(node,shard)
// slot bases: base32[t*32+sh] = rowptr[t] + sum_{s<sh} deg32[t*32+s].
__global__ __launch_bounds__(256) void k_scan3(const int* __restrict__ deg32,
                                               const int* __restrict__ boff,
                                               int* __restrict__ rowptr,
                                               int* __restrict__ base32) {
  __shared__ int wsum[4];
  const int tid = threadIdx.x, lane = tid & 63, wid = tid >> 6;
  const int node0 = blockIdx.x * 2048 + tid * 8;
  int e[8];
#pragma unroll
  for (int i = 0; i < 8; ++i) {
    const int4* p = (const int4*)(deg32 + (size_t)(node0 + i) * 32);
    int s8 = 0;
#pragma unroll
    for (int j = 0; j < 8; ++j) {
      int4 v = p[j];
      s8 += v.x + v.y + v.z + v.w;
    }
    e[i] = s8;
  }
  int s = e[0] + e[1] + e[2] + e[3] + e[4] + e[5] + e[6] + e[7];
  int incl = s;
#pragma unroll
  for (int off = 1; off < 64; off <<= 1) {
    int t = __shfl_up(incl, off, 64);
    if (lane >= off) incl += t;
  }
  if (lane == 63) wsum[wid] = incl;
  __syncthreads();
  int run = boff[blockIdx.x] + (incl - s);
  for (int w = 0; w < wid; ++w) run += wsum[w];
  int o[8];
#pragma unroll
  for (int i = 0; i < 8; ++i) { o[i] = run; run += e[i]; }
  *(int4*)(rowptr + node0) = make_int4(o[0], o[1], o[2], o[3]);
  *(int4*)(rowptr + node0 + 4) = make_int4(o[4], o[5], o[6], o[7]);
#pragma unroll
  for (int i = 0; i < 8; ++i) {
    const int4* p = (const int4*)(deg32 + (size_t)(node0 + i) * 32);
    int4* b = (int4*)(base32 + (size_t)(node0 + i) * 32);
    int r2 = o[i];
#pragma unroll
    for (int j = 0; j < 8; ++j) {
      int4 v = p[j];
      int4 bb;
      bb.x = r2;
      bb.y = r2 + v.x;
      bb.z = bb.y + v.y;
      bb.w = bb.z + v.z;
      b[j] = bb;
      r2 = bb.w + v.w;
    }
  }
}

// Atomic-free CSR fill: position = base32[tgt*32 + shard] + in-shard rank.
__global__ void k_fill(const int* __restrict__ src, const int* __restrict__ tgt,
                       const int* __restrict__ posin,
                       const int* __restrict__ base32,
                       int* __restrict__ csrc, int E) {
  int e = blockIdx.x * 256 + threadIdx.x;
  if (e >= E) return;
  int t = tgt[e];
  csrc[base32[(size_t)t * 32 + ((e >> 8) & 31)] + posin[e]] = src[e];
}

// ---------------------------------------------------------------------------
// CSR aggregate: H = relu(sum/deg + bias + Yr), bf16 rows, f32 accum.
__global__ __launch_bounds__(256) void k_agg(
    const unsigned short* __restrict__ Y, const int* __restrict__ rowptr,
    const int* __restrict__ csrc, const float* __restrict__ bias,
    const unsigned short* __restrict__ Yr, unsigned short* __restrict__ H,
    int N) {
  int node = (blockIdx.x * 256 + threadIdx.x) >> 6;
  if (node >= N) return;
  const int lane = threadIdx.x & 63;
  const int c4 = lane & 15, rr = lane >> 4;
  int beg = rowptr[node], end = rowptr[node + 1];
  float a0 = 0.f, a1 = 0.f, a2 = 0.f, a3 = 0.f;
  float b0 = 0.f, b1 = 0.f, b2 = 0.f, b3 = 0.f;
  for (int e = beg; e < end; e += 8) {
    int e0 = e + rr, e1 = e + 4 + rr;
    if (e0 < end) {
      int s = csrc[e0];
      uint2 v = *(const uint2*)(Y + (size_t)s * 64 + c4 * 4);
      a0 += bf2f(v.x & 0xffffu); a1 += bf2f(v.x >> 16);
      a2 += bf2f(v.y & 0xffffu); a3 += bf2f(v.y >> 16);
    }
    if (e1 < end) {
      int s = csrc[e1];
      uint2 v = *(const uint2*)(Y + (size_t)s * 64 + c4 * 4);
      b0 += bf2f(v.x & 0xffffu); b1 += bf2f(v.x >> 16);
      b2 += bf2f(v.y & 0xffffu); b3 += bf2f(v.y >> 16);
    }
  }
  a0 += b0; a1 += b1; a2 += b2; a3 += b3;
#pragma unroll
  for (int msk = 16; msk <= 32; msk <<= 1) {
    a0 += __shfl_xor(a0, msk, 64);
    a1 += __shfl_xor(a1, msk, 64);
    a2 += __shfl_xor(a2, msk, 64);
    a3 += __shfl_xor(a3, msk, 64);
  }
  if (rr == 0) {
    float cdeg = (float)(end - beg);
    if (cdeg < 1.f) cdeg = 1.f;
    float inv = 1.f / cdeg;
    float4 bv = *(const float4*)(bias + c4 * 4);
    uint2 yv = *(const uint2*)(Yr + (size_t)node * 64 + c4 * 4);
    float o0 = fmaxf(a0 * inv + bv.x + bf2f(yv.x & 0xffffu), 0.f);
    float o1 = fmaxf(a1 * inv + bv.y + bf2f(yv.x >> 16), 0.f);
    float o2 = fmaxf(a2 * inv + bv.z + bf2f(yv.y & 0xffffu), 0.f);
    float o3 = fmaxf(a3 * inv + bv.w + bf2f(yv.y >> 16), 0.f);
    uint2 pk;
    pk.x = (unsigned int)f2bf(o0) | ((unsigned int)f2bf(o1) << 16);
    pk.y = (unsigned int)f2bf(o2) | ((unsigned int)f2bf(o3) << 16);
    *(uint2*)(H + (size_t)node * 64 + c4 * 4) = pk;
  }
}

// ---------------------------------------------------------------------------
// MFMA edge pipeline v3 (unchanged): bf16 EA single-load A-frag, coalesced
// G row gathers, per-wave LDS C-layout redistribution.
#define T1_STRIDE 72
#define G_STRIDE 68
__global__ __launch_bounds__(256) void k_edge3(
    const unsigned short* __restrict__ EAb, const int* __restrict__ src,
    const int* __restrict__ tgt, const unsigned short* __restrict__ Gb,
    const unsigned short* __restrict__ We1T,
    const unsigned short* __restrict__ W25T,
    const float* __restrict__ cvec, const float* __restrict__ be1,
    const float* __restrict__ Wo2, const float* __restrict__ bo2,
    float* __restrict__ out, int E, int nT, int nWaves) {
  __shared__ unsigned short sT1a[4][16 * T1_STRIDE];
  __shared__ float sGa[4][16 * G_STRIDE];
  const int tid = threadIdx.x;
  const int wid = tid >> 6, lane = tid & 63;
  const int m = lane & 15, q = lane >> 4;
  unsigned short* sT1 = sT1a[wid];
  float* sG = sGa[wid];

  short8 bWe1[4], bW25[4][2];
  float cv[4], wo2v[4], be1v[4];
#pragma unroll
  for (int nt = 0; nt < 4; ++nt) {
    int n = nt * 16 + m;
    bWe1[nt] = *(const short8*)(We1T + n * 32 + q * 8);
    bW25[nt][0] = *(const short8*)(W25T + n * 64 + q * 8);
    bW25[nt][1] = *(const short8*)(W25T + n * 64 + 32 + q * 8);
    cv[nt] = cvec[n];
    wo2v[nt] = Wo2[n];
    be1v[nt] = be1[n];
  }
  const float b_out = bo2[0];
  const short8 zfrag = {};

  int t = blockIdx.x * 4 + wid;
  if (t >= nT) return;
  int il = t * 16 + m; if (il >= E) il = E - 1;
  int my_idx = (lane < 16) ? src[il] : ((lane < 32) ? tgt[il] : 0);

  while (true) {
    const int base = t * 16;
    const int tn = t + nWaves;
    const bool last = (tn >= nT);
    const int tc = last ? t : tn;

    int il_n = tc * 16 + m; if (il_n >= E) il_n = E - 1;
    int idx_n = (lane < 16) ? src[il_n] : ((lane < 32) ? tgt[il_n] : 0);

    int rs[4], rt[4];
#pragma unroll
    for (int r = 0; r < 4; ++r) {
      rs[r] = __shfl(my_idx, q * 4 + r, 64);
      rt[r] = __shfl(my_idx, 16 + q * 4 + r, 64);
    }
    uint2 sv[4], tv[4];
#pragma unroll
    for (int r = 0; r < 4; ++r) {
      sv[r] = *(const uint2*)(Gb + (size_t)rs[r] * 64 + m * 4);
      tv[r] = *(const uint2*)(Gb + (size_t)rt[r] * 64 + m * 4);
    }

    int er = base + m; if (er >= E) er = E - 1;
    short8 aEA = zfrag;
    if (q < 2) aEA = *(const short8*)(EAb + (size_t)er * 16 + (q & 1) * 8);

    f32x4 t1[4];
#pragma unroll
    for (int nt = 0; nt < 4; ++nt) {
      f32x4 cinit; cinit[0] = be1v[nt]; cinit[1] = be1v[nt];
      cinit[2] = be1v[nt]; cinit[3] = be1v[nt];
      t1[nt] = __builtin_amdgcn_mfma_f32_16x16x32_bf16(aEA, bWe1[nt], cinit, 0, 0, 0);
    }
#pragma unroll
    for (int nt = 0; nt < 4; ++nt)
#pragma unroll
      for (int r = 0; r < 4; ++r)
        sT1[(q * 4 + r) * T1_STRIDE + nt * 16 + m] = f2bf(fmaxf(t1[nt][r], 0.f));
    short8 aT0 = *(short8*)(sT1 + m * T1_STRIDE + q * 8);
    short8 aT1 = *(short8*)(sT1 + m * T1_STRIDE + 32 + q * 8);

#pragma unroll
    for (int r = 0; r < 4; ++r) {
      f32x4 g;
      g[0] = bf2f(sv[r].x & 0xffffu) + bf2f(tv[r].x & 0xffffu);
      g[1] = bf2f(sv[r].x >> 16)     + bf2f(tv[r].x >> 16);
      g[2] = bf2f(sv[r].y & 0xffffu) + bf2f(tv[r].y & 0xffffu);
      g[3] = bf2f(sv[r].y >> 16)     + bf2f(tv[r].y >> 16);
      *(f32x4*)(sG + (q * 4 + r) * G_STRIDE + m * 4) = g;
    }

    f32x4 acc[4];
#pragma unroll
    for (int nt = 0; nt < 4; ++nt)
#pragma unroll
      for (int r = 0; r < 4; ++r)
        acc[nt][r] = cv[nt] + sG[(q * 4 + r) * G_STRIDE + nt * 16 + m];
#pragma unroll
    for (int nt = 0; nt < 4; ++nt) {
      acc[nt] = __builtin_amdgcn_mfma_f32_16x16x32_bf16(aT0, bW25[nt][0], acc[nt], 0, 0, 0);
      acc[nt] = __builtin_amdgcn_mfma_f32_16x16x32_bf16(aT1, bW25[nt][1], acc[nt], 0, 0, 0);
    }

    float p[4];
#pragma unroll
    for (int r = 0; r < 4; ++r) {
      p[r] = fmaxf(acc[0][r], 0.f) * wo2v[0] + fmaxf(acc[1][r], 0.f) * wo2v[1] +
             fmaxf(acc[2][r], 0.f) * wo2v[2] + fmaxf(acc[3][r], 0.f) * wo2v[3];
    }
#pragma unroll
    for (int msk = 1; msk <= 8; msk <<= 1) {
#pragma unroll
      for (int r = 0; r < 4; ++r) p[r] += __shfl_xor(p[r], msk, 64);
    }
    if (m == 0) {
#pragma unroll
      for (int r = 0; r < 4; ++r) {
        int row = base + q * 4 + r;
        if (row < E) out[row] = 1.f / (1.f + __expf(-(p[r] + b_out)));
      }
    }

    if (last) break;
    t = tn; my_idx = idx_n;
  }
}

// ---------------------------------------------------------------------------
extern "C" void kernel_launch(void* const* d_in, const int* in_sizes, int n_in,
                              void* d_out, int out_size, void* d_ws, size_t ws_size,
                              hipStream_t stream) {
  const float* x     = (const float*)d_in[0];
  const unsigned int* eidx = (const unsigned int*)d_in[1];
  const float* eattr = (const float*)d_in[2];
  const float* We1 = (const float*)d_in[3];
  const float* be1 = (const float*)d_in[4];
  const float* We2 = (const float*)d_in[5];
  const float* be2 = (const float*)d_in[6];
  const float* Wl0 = (const float*)d_in[7];
  const float* bl0 = (const float*)d_in[8];
  const float* Wr0 = (const float*)d_in[9];
  const float* Wl1 = (const float*)d_in[10];
  const float* bl1 = (const float*)d_in[11];
  const float* Wr1 = (const float*)d_in[12];
  const float* Wo1 = (const float*)d_in[13];
  const float* bo1 = (const float*)d_in[14];
  const float* Wo2 = (const float*)d_in[15];
  const float* bo2 = (const float*)d_in[16];

  const int N = in_sizes[0] / 128;   // 100000
  const int E = in_sizes[2] / 16;    // 1000000
  const int padN = (N + 2047) & ~2047;
  const int nB = padN / 2048;
  float* out = (float*)d_out;

  char* ws = (char*)d_ws;
  size_t off = 0;
  auto alloc = [&](size_t bytes) {
    char* p = ws + off;
    off += (bytes + 255) & ~(size_t)255;
    return p;
  };
  unsigned int* flag = (unsigned int*)alloc(256);
  int* src    = (int*)alloc((size_t)E * 4);
  int* tgt    = (int*)alloc((size_t)E * 4);
  int* posin  = (int*)alloc((size_t)E * 4);
  int* rowptr = (int*)alloc((size_t)(padN + 64) * 4);
  int* bsum   = (int*)alloc(64 * 4);
  int* boff   = (int*)alloc(64 * 4);
  int* csrc   = (int*)alloc((size_t)E * 4);
  unsigned short* EAb = (unsigned short*)alloc((size_t)E * 16 * 2);
  // Hb buffer doubles as base32 (disjoint lifetimes: base32 scan3->fill,
  // Hb agg0->...). padN*64*2 bytes == padN*32*4 bytes == padN*128.
  char* HbB = alloc((size_t)padN * 128);
  unsigned short* Hb = (unsigned short*)HbB;
  int* base32 = (int*)HbB;
  unsigned short* Yl = (unsigned short*)alloc((size_t)N * 64 * 2);
  unsigned short* Yr = (unsigned short*)alloc((size_t)N * 64 * 2);
  // Gb buffer doubles as deg32 (deg32 dead after scan3; Gb written at ngemm2).
  char* GbB = alloc((size_t)padN * 128);
  unsigned short* Gb = (unsigned short*)GbB;
  int* deg32 = (int*)GbB;
  unsigned short* W25T = (unsigned short*)alloc(64 * 64 * 2);
  unsigned short* We1T = (unsigned short*)alloc(64 * 32 * 2);
  unsigned short* Wo1T = (unsigned short*)alloc(64 * 64 * 2);
  unsigned short* WnT1 = (unsigned short*)alloc(128 * 64 * 2);
  float* cvec = (float*)alloc(64 * 4);
  (void)ws_size; (void)n_in; (void)out_size;

  k_flag<<<256, 256, 0, stream>>>(eidx, 8192, flag, deg32, padN * 32);

  // MEGA1: decode + prep + WnT1 + layer-0 GEMM (inline weights) + eattr conv
  const int nDec = (E + 255) / 256;
  const int gB = (N + 63) / 64;
  const int convB = 1024;
  const int nWork = 33 + gB + convB;
  k_mega1<<<nDec + nWork, 256, 0, stream>>>(
      eidx, flag, E, nDec, nWork, gB, convB * 256,
      src, tgt, posin, deg32,
      x, Yl, Yr, N,
      We2, Wo1, be2, bo1, We1, Wl0, Wr0, Wl1, Wr1,
      W25T, We1T, Wo1T, cvec, WnT1,
      (const float4*)eattr, (uint2*)EAb);

  k_scan1<<<nB, 256, 0, stream>>>(deg32, bsum);
  k_scan2<<<1, 64, 0, stream>>>(bsum, boff, nB);
  k_scan3<<<nB, 256, 0, stream>>>(deg32, boff, rowptr, base32);
  k_fill<<<nDec, 256, 0, stream>>>(src, tgt, posin, base32, csrc, E);

  const int aggB = (N + 3) / 4;
  k_agg<<<aggB, 256, 0, stream>>>(Yl, rowptr, csrc, bl0, Yr, Hb, N);

  // Layer 1
  k_ngemm<64, true, 2><<<gB, 256, 0, stream>>>(Hb, WnT1, Yl, Yr, N);
  k_agg<<<aggB, 256, 0, stream>>>(Yl, rowptr, csrc, bl1, Yr, Hb, N);

  // G = H2 @ Wo1
  k_ngemm<64, true, 1><<<gB, 256, 0, stream>>>(Hb, Wo1T, Gb, nullptr, N);

  // MFMA edge pipeline v3
  const int nT = (E + 15) / 16;
  const int blocks = 3072;
  k_edge3<<<blocks, 256, 0, stream>>>(EAb, src, tgt, Gb, We1T, W25T, cvec,
                                      be1, Wo2, bo2, out, E, nT, blocks * 4);
}

// Round 2
// 398.636 us; speedup vs baseline: 1.1638x; 1.1638x over previous
//
#include <hip/hip_runtime.h>
#include <math.h>

typedef __attribute__((ext_vector_type(8))) short short8;
typedef __attribute__((ext_vector_type(4))) float f32x4;

#define CAPB 4096   // fixed capacity per coarse bucket (mean 2558, 30 sigma)

static __device__ __forceinline__ unsigned short f2bf(float f) {
  union { float f; unsigned int u; } x; x.f = f;
  unsigned int r = x.u + 0x7fffu + ((x.u >> 16) & 1u);  // RNE
  return (unsigned short)(r >> 16);
}
static __device__ __forceinline__ float bf2f(unsigned int u) {
  union { unsigned int u; float f; } x; x.u = u << 16; return x.f;
}

// ---------------------------------------------------------------------------
// Block 0: int64-vs-int32 edge_index detection. Block 1: zero gcursor[512].
__global__ void k_flag(const unsigned int* __restrict__ w, int nSample,
                       unsigned int* __restrict__ flag,
                       int* __restrict__ gcursor) {
  if (blockIdx.x == 1) {
    if (threadIdx.x < 256) { gcursor[threadIdx.x] = 0; gcursor[threadIdx.x + 256] = 0; }
    return;
  }
  if (blockIdx.x != 0) return;
  __shared__ unsigned int red[256];
  unsigned int v = 0;
  for (int i = threadIdx.x; i < nSample; i += 256) v |= w[2 * i + 1];
  red[threadIdx.x] = v;
  __syncthreads();
  for (int s = 128; s > 0; s >>= 1) {
    if (threadIdx.x < s) red[threadIdx.x] |= red[threadIdx.x + s];
    __syncthreads();
  }
  if (threadIdx.x == 0) flag[0] = red[0];  // nonzero => int32 layout
}

// ---------------------------------------------------------------------------
// MFMA node GEMM body. INLINEW: build B fragments directly from f32 W0/W1
// (no dependency on prep blocks -> safe to co-dispatch in one mega kernel).
// MFMA layouts (gfx950, verified): A[m=lane&15][k=(lane>>4)*8+j],
// B[k][n=lane&15], C/D col=lane&15, row=(lane>>4)*4+reg.
template <int K, bool BF16IN, int NTILES, bool INLINEW>
__device__ __forceinline__ void ngemm_body(
    const void* __restrict__ Xv, const unsigned short* __restrict__ WnT,
    const float* __restrict__ W0f, const float* __restrict__ W1f,
    unsigned short* __restrict__ Y0, unsigned short* __restrict__ Y1,
    int N, int blk, unsigned short* __restrict__ sX) {
  constexpr int STR = K + 8;
  constexpr int NC = K / 32;
  const int tid = threadIdx.x;
  const int wv = tid >> 6, lane = tid & 63;
  const int m = lane & 15, q = lane >> 4;
  const int row0 = blk * 64;

  short8 bB[NTILES][NC];
#pragma unroll
  for (int ct = 0; ct < NTILES; ++ct)
#pragma unroll
    for (int c = 0; c < NC; ++c) {
      if constexpr (INLINEW) {
        int n = (NTILES == 2) ? (wv * 32 + ct * 16 + m) : (wv * 16 + m);
        const float* Wf = (n < 64) ? W0f : W1f;
        int nn = n & 63;
        union { short8 s; unsigned short h[8]; } ub;
#pragma unroll
        for (int j = 0; j < 8; ++j)
          ub.h[j] = f2bf(Wf[(size_t)(c * 32 + q * 8 + j) * 64 + nn]);
        bB[ct][c] = ub.s;
      } else {
        int n = (NTILES == 2) ? (wv * 32 + ct * 16 + m) : (wv * 16 + m);
        bB[ct][c] = *(const short8*)(WnT + (size_t)n * K + c * 32 + q * 8);
      }
    }

#pragma unroll
  for (int i = 0; i < K / 16; ++i) {
    int f = tid + 256 * i;
    int r = f / (K / 4);
    int c4 = f % (K / 4);
    int rr = row0 + r; if (rr >= N) rr = N - 1;
    uint2 pk;
    if constexpr (BF16IN) {
      pk = *(const uint2*)((const unsigned short*)Xv + (size_t)rr * K + c4 * 4);
    } else {
      float4 v = *(const float4*)((const float*)Xv + (size_t)rr * K + c4 * 4);
      pk.x = (unsigned int)f2bf(v.x) | ((unsigned int)f2bf(v.y) << 16);
      pk.y = (unsigned int)f2bf(v.z) | ((unsigned int)f2bf(v.w) << 16);
    }
    *(uint2*)(sX + r * STR + c4 * 4) = pk;
  }
  __syncthreads();

  f32x4 acc[4][NTILES];
#pragma unroll
  for (int rt = 0; rt < 4; ++rt)
#pragma unroll
    for (int ct = 0; ct < NTILES; ++ct)
#pragma unroll
      for (int r = 0; r < 4; ++r) acc[rt][ct][r] = 0.f;

#pragma unroll
  for (int c = 0; c < NC; ++c) {
    short8 a[4];
#pragma unroll
    for (int rt = 0; rt < 4; ++rt)
      a[rt] = *(const short8*)(sX + (rt * 16 + m) * STR + c * 32 + q * 8);
#pragma unroll
    for (int rt = 0; rt < 4; ++rt)
#pragma unroll
      for (int ct = 0; ct < NTILES; ++ct)
        acc[rt][ct] = __builtin_amdgcn_mfma_f32_16x16x32_bf16(a[rt], bB[ct][c], acc[rt][ct], 0, 0, 0);
  }

#pragma unroll
  for (int rt = 0; rt < 4; ++rt)
#pragma unroll
    for (int ct = 0; ct < NTILES; ++ct) {
      unsigned short* Yw;
      int n;
      if constexpr (NTILES == 2) {
        Yw = (wv < 2) ? Y0 : Y1;
        n = (wv & 1) * 32 + ct * 16 + m;
      } else {
        Yw = Y0;
        n = wv * 16 + m;
      }
#pragma unroll
      for (int reg = 0; reg < 4; ++reg) {
        int row = row0 + rt * 16 + q * 4 + reg;
        if (row < N) Yw[(size_t)row * 64 + n] = f2bf(acc[rt][ct][reg]);
      }
    }
}

template <int K, bool BF16IN, int NTILES>
__global__ __launch_bounds__(256) void k_ngemm(
    const void* __restrict__ Xv, const unsigned short* __restrict__ WnT,
    unsigned short* __restrict__ Y0, unsigned short* __restrict__ Y1, int N) {
  __shared__ __align__(16) unsigned short sX[64 * (K + 8)];
  ngemm_body<K, BF16IN, NTILES, false>(Xv, WnT, nullptr, nullptr, Y0, Y1, N,
                                       blockIdx.x, sX);
}

// ---------------------------------------------------------------------------
// MEGA1: decode+bucket-scatter + prep + WnT1 + layer-0 GEMM + eattr conv.
// Decode-scatter (4096 edges/block): LDS hist over 391 coarse buckets
// (tgt>>8), ONE returning global atomic per (block,bucket) (~96K total, vs
// 1M per-edge before: round-1 showed returning-atomic throughput ~13 Gops/s
// flat regardless of addresses), then LDS-cursor scatter of packed
// (src<<8 | tgt&255) words into fixed-capacity bucket regions.
__global__ __launch_bounds__(256) void k_mega1(
    const unsigned int* __restrict__ w, const unsigned int* __restrict__ flag,
    int E, int nDec, int nWork, int gB, int nConvThreads,
    int* __restrict__ src, int* __restrict__ tgt,
    int* __restrict__ gcursor, unsigned int* __restrict__ tmp,
    const float* __restrict__ x, unsigned short* __restrict__ Yl,
    unsigned short* __restrict__ Yr, int N,
    const float* __restrict__ We2, const float* __restrict__ Wo1,
    const float* __restrict__ be2, const float* __restrict__ bo1,
    const float* __restrict__ We1,
    const float* __restrict__ Wl0, const float* __restrict__ Wr0,
    const float* __restrict__ Wl1, const float* __restrict__ Wr1,
    unsigned short* __restrict__ W25T, unsigned short* __restrict__ We1T,
    unsigned short* __restrict__ Wo1T, float* __restrict__ cvec,
    unsigned short* __restrict__ WnT1,
    const float4* __restrict__ ef, uint2* __restrict__ eb) {
  __shared__ __align__(16) char smem[64 * 136 * 2];   // 17408 B, union use
  const int tid = threadIdx.x;
  const int tot = nDec + nWork;
  // proportional striping: decode-count before this block
  const int di  = (int)(((long long)blockIdx.x * nDec) / tot);
  const int di1 = (int)(((long long)(blockIdx.x + 1) * nDec) / tot);

  if (di1 > di) {
    // ---- decode+scatter block #di: edges [di*4096, min(E, +4096))
    int* hist = (int*)smem;   // 512 ints
    hist[tid] = 0; hist[tid + 256] = 0;
    __syncthreads();
    const int e0 = di * 4096;
    const int e1 = (e0 + 4096 < E) ? (e0 + 4096) : E;
    const unsigned int fl = flag[0];
    // pass1: decode + store src/tgt + LDS hist over coarse buckets
    for (int e = e0 + tid; e < e1; e += 256) {
      int s, t;
      if (fl) { s = (int)w[e]; t = (int)w[E + e]; }
      else    { s = (int)w[2 * e]; t = (int)w[2 * (E + e)]; }
      src[e] = s; tgt[e] = t;
      atomicAdd(hist + (t >> 8), 1);
    }
    __syncthreads();
    // pass2: reserve contiguous ranges in each bucket region
    {
      int c0 = hist[tid], c1 = hist[tid + 256];
      int s0 = (c0 > 0) ? atomicAdd(gcursor + tid, c0) : 0;
      int s1 = (c1 > 0) ? atomicAdd(gcursor + tid + 256, c1) : 0;
      __syncthreads();
      hist[tid] = s0; hist[tid + 256] = s1;
    }
    __syncthreads();
    // pass3: scatter packed (src<<8 | tgt&255) via LDS cursors
    for (int e = e0 + tid; e < e1; e += 256) {
      int s, t;
      if (fl) { s = (int)w[e]; t = (int)w[E + e]; }
      else    { s = (int)w[2 * e]; t = (int)w[2 * (E + e)]; }
      int b = t >> 8;
      int pos = atomicAdd(hist + b, 1);
      if (pos < CAPB)
        tmp[(size_t)b * CAPB + pos] = ((unsigned int)s << 8) | (unsigned int)(t & 255);
    }
    return;
  }
  const int wi = blockIdx.x - di;
  if (wi == 0) {
    // ---- prep: W25T=(We2@Wo1)^T, Wo1T, We1T, cvec (Wo1 staged in smem)
    float* sB = (float*)smem;
    for (int i = tid; i < 1024; i += 256)
      *(float4*)&sB[i * 4] = *(const float4*)(Wo1 + i * 4);
    __syncthreads();
    for (int idx = tid; idx < 4096; idx += 256) {
      int k = idx >> 6, n = idx & 63;   // k wave-uniform -> We2 scalarizes
      float s = 0.f;
#pragma unroll 8
      for (int mm = 0; mm < 64; ++mm) s = fmaf(We2[k * 64 + mm], sB[mm * 64 + n], s);
      W25T[n * 64 + k] = f2bf(s);
      Wo1T[n * 64 + k] = f2bf(sB[k * 64 + n]);
    }
    for (int idx = tid; idx < 2048; idx += 256) {
      int n = idx >> 5, k = idx & 31;
      We1T[n * 32 + k] = (k < 16) ? f2bf(We1[k * 64 + n]) : (unsigned short)0;
    }
    if (tid < 64) {
      float s = bo1[tid];
#pragma unroll 8
      for (int mm = 0; mm < 64; ++mm) s = fmaf(be2[mm], sB[mm * 64 + tid], s);
      cvec[tid] = s;
    }
  } else if (wi <= 32) {
    // ---- WnT1 transpose (128x64)
    int idx = (wi - 1) * 256 + tid;
    int n = idx >> 6, k = idx & 63;
    float v = (n < 64) ? Wl1[(size_t)k * 64 + n] : Wr1[(size_t)k * 64 + (n - 64)];
    WnT1[idx] = f2bf(v);
  } else if (wi < 33 + gB) {
    // ---- layer-0 GEMM (inline f32 weights)
    ngemm_body<128, false, 2, true>(x, nullptr, Wl0, Wr0, Yl, Yr, N,
                                    wi - 33, (unsigned short*)smem);
  } else {
    // ---- eattr f32 -> bf16
    int gid = (wi - 33 - gB) * 256 + tid;
    int nItems = E * 4;
    for (int i = gid; i < nItems; i += nConvThreads) {
      float4 v = ef[i];
      uint2 pk;
      pk.x = (unsigned int)f2bf(v.x) | ((unsigned int)f2bf(v.y) << 16);
      pk.y = (unsigned int)f2bf(v.z) | ((unsigned int)f2bf(v.w) << 16);
      eb[i] = pk;
    }
  }
}

// ---------------------------------------------------------------------------
// Per-bucket counting sort: bucket b holds edges with tgt in [b*256,b*256+256)
// as packed (src<<8 | tgt&255) words. LDS count per node-local bin ->
// exclusive scan -> rowptr2[node]={beg,end} (absolute into csrc's CAP layout)
// -> LDS-cursor scatter of src into csrc. Order within a node is arbitrary
// (aggregation is order-invariant).
__global__ __launch_bounds__(256) void k_bsort(
    const unsigned int* __restrict__ tmp, const int* __restrict__ gcursor,
    int* __restrict__ csrc, uint2* __restrict__ rowptr2, int N) {
  __shared__ int cnt[256];
  __shared__ int curs[256];
  __shared__ int wsum[4];
  const int b = blockIdx.x, tid = threadIdx.x;
  int c = gcursor[b]; if (c > CAPB) c = CAPB;
  cnt[tid] = 0;
  __syncthreads();
  const unsigned int* reg = tmp + (size_t)b * CAPB;
  for (int i = tid; i < c; i += 256) atomicAdd(&cnt[reg[i] & 255u], 1);
  __syncthreads();
  // block-wide exclusive scan of cnt[256]
  const int lane = tid & 63, wv = tid >> 6;
  int v = cnt[tid];
  int incl = v;
#pragma unroll
  for (int off = 1; off < 64; off <<= 1) {
    int t = __shfl_up(incl, off, 64);
    if (lane >= off) incl += t;
  }
  if (lane == 63) wsum[wv] = incl;
  __syncthreads();
  int add = 0;
  for (int ww = 0; ww < wv; ++ww) add += wsum[ww];
  int excl = add + incl - v;
  curs[tid] = excl;
  int node = b * 256 + tid;
  if (node < N)
    rowptr2[node] = make_uint2((unsigned int)(b * CAPB + excl),
                               (unsigned int)(b * CAPB + excl + v));
  __syncthreads();
  for (int i = tid; i < c; i += 256) {
    unsigned int wd = reg[i];
    int p = atomicAdd(&curs[wd & 255u], 1);
    csrc[(size_t)b * CAPB + p] = (int)(wd >> 8);
  }
}

// ---------------------------------------------------------------------------
// CSR aggregate: H = relu(sum/deg + bias + Yr), bf16 rows, f32 accum.
__global__ __launch_bounds__(256) void k_agg(
    const unsigned short* __restrict__ Y, const uint2* __restrict__ rowptr2,
    const int* __restrict__ csrc, const float* __restrict__ bias,
    const unsigned short* __restrict__ Yr, unsigned short* __restrict__ H,
    int N) {
  int node = (blockIdx.x * 256 + threadIdx.x) >> 6;
  if (node >= N) return;
  const int lane = threadIdx.x & 63;
  const int c4 = lane & 15, rr = lane >> 4;
  uint2 be = rowptr2[node];
  int beg = (int)be.x, end = (int)be.y;
  float a0 = 0.f, a1 = 0.f, a2 = 0.f, a3 = 0.f;
  float b0 = 0.f, b1 = 0.f, b2 = 0.f, b3 = 0.f;
  for (int e = beg; e < end; e += 8) {
    int e0 = e + rr, e1 = e + 4 + rr;
    if (e0 < end) {
      int s = csrc[e0];
      uint2 v = *(const uint2*)(Y + (size_t)s * 64 + c4 * 4);
      a0 += bf2f(v.x & 0xffffu); a1 += bf2f(v.x >> 16);
      a2 += bf2f(v.y & 0xffffu); a3 += bf2f(v.y >> 16);
    }
    if (e1 < end) {
      int s = csrc[e1];
      uint2 v = *(const uint2*)(Y + (size_t)s * 64 + c4 * 4);
      b0 += bf2f(v.x & 0xffffu); b1 += bf2f(v.x >> 16);
      b2 += bf2f(v.y & 0xffffu); b3 += bf2f(v.y >> 16);
    }
  }
  a0 += b0; a1 += b1; a2 += b2; a3 += b3;
#pragma unroll
  for (int msk = 16; msk <= 32; msk <<= 1) {
    a0 += __shfl_xor(a0, msk, 64);
    a1 += __shfl_xor(a1, msk, 64);
    a2 += __shfl_xor(a2, msk, 64);
    a3 += __shfl_xor(a3, msk, 64);
  }
  if (rr == 0) {
    float cdeg = (float)(end - beg);
    if (cdeg < 1.f) cdeg = 1.f;
    float inv = 1.f / cdeg;
    float4 bv = *(const float4*)(bias + c4 * 4);
    uint2 yv = *(const uint2*)(Yr + (size_t)node * 64 + c4 * 4);
    float o0 = fmaxf(a0 * inv + bv.x + bf2f(yv.x & 0xffffu), 0.f);
    float o1 = fmaxf(a1 * inv + bv.y + bf2f(yv.x >> 16), 0.f);
    float o2 = fmaxf(a2 * inv + bv.z + bf2f(yv.y & 0xffffu), 0.f);
    float o3 = fmaxf(a3 * inv + bv.w + bf2f(yv.y >> 16), 0.f);
    uint2 pk;
    pk.x = (unsigned int)f2bf(o0) | ((unsigned int)f2bf(o1) << 16);
    pk.y = (unsigned int)f2bf(o2) | ((unsigned int)f2bf(o3) << 16);
    *(uint2*)(H + (size_t)node * 64 + c4 * 4) = pk;
  }
}

// ---------------------------------------------------------------------------
// MFMA edge pipeline v3 (unchanged): bf16 EA single-load A-frag, coalesced
// G row gathers, per-wave LDS C-layout redistribution.
#define T1_STRIDE 72
#define G_STRIDE 68
__global__ __launch_bounds__(256) void k_edge3(
    const unsigned short* __restrict__ EAb, const int* __restrict__ src,
    const int* __restrict__ tgt, const unsigned short* __restrict__ Gb,
    const unsigned short* __restrict__ We1T,
    const unsigned short* __restrict__ W25T,
    const float* __restrict__ cvec, const float* __restrict__ be1,
    const float* __restrict__ Wo2, const float* __restrict__ bo2,
    float* __restrict__ out, int E, int nT, int nWaves) {
  __shared__ unsigned short sT1a[4][16 * T1_STRIDE];
  __shared__ float sGa[4][16 * G_STRIDE];
  const int tid = threadIdx.x;
  const int wid = tid >> 6, lane = tid & 63;
  const int m = lane & 15, q = lane >> 4;
  unsigned short* sT1 = sT1a[wid];
  float* sG = sGa[wid];

  short8 bWe1[4], bW25[4][2];
  float cv[4], wo2v[4], be1v[4];
#pragma unroll
  for (int nt = 0; nt < 4; ++nt) {
    int n = nt * 16 + m;
    bWe1[nt] = *(const short8*)(We1T + n * 32 + q * 8);
    bW25[nt][0] = *(const short8*)(W25T + n * 64 + q * 8);
    bW25[nt][1] = *(const short8*)(W25T + n * 64 + 32 + q * 8);
    cv[nt] = cvec[n];
    wo2v[nt] = Wo2[n];
    be1v[nt] = be1[n];
  }
  const float b_out = bo2[0];
  const short8 zfrag = {};

  int t = blockIdx.x * 4 + wid;
  if (t >= nT) return;
  int il = t * 16 + m; if (il >= E) il = E - 1;
  int my_idx = (lane < 16) ? src[il] : ((lane < 32) ? tgt[il] : 0);

  while (true) {
    const int base = t * 16;
    const int tn = t + nWaves;
    const bool last = (tn >= nT);
    const int tc = last ? t : tn;

    int il_n = tc * 16 + m; if (il_n >= E) il_n = E - 1;
    int idx_n = (lane < 16) ? src[il_n] : ((lane < 32) ? tgt[il_n] : 0);

    int rs[4], rt[4];
#pragma unroll
    for (int r = 0; r < 4; ++r) {
      rs[r] = __shfl(my_idx, q * 4 + r, 64);
      rt[r] = __shfl(my_idx, 16 + q * 4 + r, 64);
    }
    uint2 sv[4], tv[4];
#pragma unroll
    for (int r = 0; r < 4; ++r) {
      sv[r] = *(const uint2*)(Gb + (size_t)rs[r] * 64 + m * 4);
      tv[r] = *(const uint2*)(Gb + (size_t)rt[r] * 64 + m * 4);
    }

    int er = base + m; if (er >= E) er = E - 1;
    short8 aEA = zfrag;
    if (q < 2) aEA = *(const short8*)(EAb + (size_t)er * 16 + (q & 1) * 8);

    f32x4 t1[4];
#pragma unroll
    for (int nt = 0; nt < 4; ++nt) {
      f32x4 cinit; cinit[0] = be1v[nt]; cinit[1] = be1v[nt];
      cinit[2] = be1v[nt]; cinit[3] = be1v[nt];
      t1[nt] = __builtin_amdgcn_mfma_f32_16x16x32_bf16(aEA, bWe1[nt], cinit, 0, 0, 0);
    }
#pragma unroll
    for (int nt = 0; nt < 4; ++nt)
#pragma unroll
      for (int r = 0; r < 4; ++r)
        sT1[(q * 4 + r) * T1_STRIDE + nt * 16 + m] = f2bf(fmaxf(t1[nt][r], 0.f));
    short8 aT0 = *(short8*)(sT1 + m * T1_STRIDE + q * 8);
    short8 aT1 = *(short8*)(sT1 + m * T1_STRIDE + 32 + q * 8);

#pragma unroll
    for (int r = 0; r < 4; ++r) {
      f32x4 g;
      g[0] = bf2f(sv[r].x & 0xffffu) + bf2f(tv[r].x & 0xffffu);
      g[1] = bf2f(sv[r].x >> 16)     + bf2f(tv[r].x >> 16);
      g[2] = bf2f(sv[r].y & 0xffffu) + bf2f(tv[r].y & 0xffffu);
      g[3] = bf2f(sv[r].y >> 16)     + bf2f(tv[r].y >> 16);
      *(f32x4*)(sG + (q * 4 + r) * G_STRIDE + m * 4) = g;
    }

    f32x4 acc[4];
#pragma unroll
    for (int nt = 0; nt < 4; ++nt)
#pragma unroll
      for (int r = 0; r < 4; ++r)
        acc[nt][r] = cv[nt] + sG[(q * 4 + r) * G_STRIDE + nt * 16 + m];
#pragma unroll
    for (int nt = 0; nt < 4; ++nt) {
      acc[nt] = __builtin_amdgcn_mfma_f32_16x16x32_bf16(aT0, bW25[nt][0], acc[nt], 0, 0, 0);
      acc[nt] = __builtin_amdgcn_mfma_f32_16x16x32_bf16(aT1, bW25[nt][1], acc[nt], 0, 0, 0);
    }

    float p[4];
#pragma unroll
    for (int r = 0; r < 4; ++r) {
      p[r] = fmaxf(acc[0][r], 0.f) * wo2v[0] + fmaxf(acc[1][r], 0.f) * wo2v[1] +
             fmaxf(acc[2][r], 0.f) * wo2v[2] + fmaxf(acc[3][r], 0.f) * wo2v[3];
    }
#pragma unroll
    for (int msk = 1; msk <= 8; msk <<= 1) {
#pragma unroll
      for (int r = 0; r < 4; ++r) p[r] += __shfl_xor(p[r], msk, 64);
    }
    if (m == 0) {
#pragma unroll
      for (int r = 0; r < 4; ++r) {
        int row = base + q * 4 + r;
        if (row < E) out[row] = 1.f / (1.f + __expf(-(p[r] + b_out)));
      }
    }

    if (last) break;
    t = tn; my_idx = idx_n;
  }
}

// ---------------------------------------------------------------------------
extern "C" void kernel_launch(void* const* d_in, const int* in_sizes, int n_in,
                              void* d_out, int out_size, void* d_ws, size_t ws_size,
                              hipStream_t stream) {
  const float* x     = (const float*)d_in[0];
  const unsigned int* eidx = (const unsigned int*)d_in[1];
  const float* eattr = (const float*)d_in[2];
  const float* We1 = (const float*)d_in[3];
  const float* be1 = (const float*)d_in[4];
  const float* We2 = (const float*)d_in[5];
  const float* be2 = (const float*)d_in[6];
  const float* Wl0 = (const float*)d_in[7];
  const float* bl0 = (const float*)d_in[8];
  const float* Wr0 = (const float*)d_in[9];
  const float* Wl1 = (const float*)d_in[10];
  const float* bl1 = (const float*)d_in[11];
  const float* Wr1 = (const float*)d_in[12];
  const float* Wo1 = (const float*)d_in[13];
  const float* bo1 = (const float*)d_in[14];
  const float* Wo2 = (const float*)d_in[15];
  const float* bo2 = (const float*)d_in[16];

  const int N = in_sizes[0] / 128;   // 100000
  const int E = in_sizes[2] / 16;    // 1000000
  const int NBUCK = (N + 255) >> 8;  // 391 coarse buckets (tgt>>8)
  float* out = (float*)d_out;

  char* ws = (char*)d_ws;
  size_t off = 0;
  auto alloc = [&](size_t bytes) {
    char* p = ws + off;
    off += (bytes + 255) & ~(size_t)255;
    return p;
  };
  unsigned int* flag = (unsigned int*)alloc(256);
  int* src    = (int*)alloc((size_t)E * 4);
  int* tgt    = (int*)alloc((size_t)E * 4);
  int* gcursor = (int*)alloc(512 * 4);
  unsigned int* tmp = (unsigned int*)alloc((size_t)NBUCK * CAPB * 4);
  int* csrc   = (int*)alloc((size_t)NBUCK * CAPB * 4);
  uint2* rowptr2 = (uint2*)alloc((size_t)N * 8);
  unsigned short* EAb = (unsigned short*)alloc((size_t)E * 16 * 2);
  unsigned short* Hb = (unsigned short*)alloc((size_t)N * 64 * 2);
  unsigned short* Yl = (unsigned short*)alloc((size_t)N * 64 * 2);
  unsigned short* Yr = (unsigned short*)alloc((size_t)N * 64 * 2);
  unsigned short* Gb = (unsigned short*)alloc((size_t)N * 64 * 2);
  unsigned short* W25T = (unsigned short*)alloc(64 * 64 * 2);
  unsigned short* We1T = (unsigned short*)alloc(64 * 32 * 2);
  unsigned short* Wo1T = (unsigned short*)alloc(64 * 64 * 2);
  unsigned short* WnT1 = (unsigned short*)alloc(128 * 64 * 2);
  float* cvec = (float*)alloc(64 * 4);
  (void)ws_size; (void)n_in; (void)out_size;

  k_flag<<<2, 256, 0, stream>>>(eidx, 8192, flag, gcursor);

  // MEGA1: decode+scatter + prep + WnT1 + layer-0 GEMM + eattr conv
  const int nDec = (E + 4095) / 4096;   // 245 decode+scatter blocks
  const int gB = (N + 63) / 64;
  const int convB = 1024;
  const int nWork = 33 + gB + convB;
  k_mega1<<<nDec + nWork, 256, 0, stream>>>(
      eidx, flag, E, nDec, nWork, gB, convB * 256,
      src, tgt, gcursor, tmp,
      x, Yl, Yr, N,
      We2, Wo1, be2, bo1, We1, Wl0, Wr0, Wl1, Wr1,
      W25T, We1T, Wo1T, cvec, WnT1,
      (const float4*)eattr, (uint2*)EAb);

  // per-bucket counting sort -> csrc + rowptr2
  k_bsort<<<NBUCK, 256, 0, stream>>>(tmp, gcursor, csrc, rowptr2, N);

  const int aggB = (N + 3) / 4;
  k_agg<<<aggB, 256, 0, stream>>>(Yl, rowptr2, csrc, bl0, Yr, Hb, N);

  // Layer 1
  k_ngemm<64, true, 2><<<gB, 256, 0, stream>>>(Hb, WnT1, Yl, Yr, N);
  k_agg<<<aggB, 256, 0, stream>>>(Yl, rowptr2, csrc, bl1, Yr, Hb, N);

  // G = H2 @ Wo1
  k_ngemm<64, true, 1><<<gB, 256, 0, stream>>>(Hb, Wo1T, Gb, nullptr, N);

  // MFMA edge pipeline v3
  const int nT = (E + 15) / 16;
  const int blocks = 3072;
  k_edge3<<<blocks, 256, 0, stream>>>(EAb, src, tgt, Gb, We1T, W25T, cvec,
                                      be1, Wo2, bo2, out, E, nT, blocks * 4);
}